// Round 8
// baseline (163.664 us; speedup 1.0000x reference)
//
#include <hip/hip_runtime.h>

// Conv2d 3x3 pad1 stride1, x[1,256,224,224] f32, w[256,256,3,3] f32 -> out[256,224,224] f32
// Implicit GEMM: M=256 (co), N=50176 (h*224+w), K=2304 (tap-major: k = (dh*3+dw)*256 + ci)
// R14: MFMA shape switch on R13. R11/R12/R13 (78/71/71us) proved sync structure is NOT
//      binding; residual is MFMA pipe-rate + issue. 32x32x16_bf16 (ceiling 2382-2495 TF
//      vs 2075-2176 for 16x16 = +15-20%) and HALF the MFMA instructions per half-tile.
//      LDS image/staging/swizzle/sync byte-identical to R13: R12 swizzle slot=c^((r>>1)&3)
//      is conflict-free for the 32x32 read pattern too (quad8 = 4(r&1) + c^((r>>1)&3),
//      rows 0-31 x both k-halves -> 8 lanes per bank-quad exactly). New read addressing:
//      lane reads row l&31, chunk 2s+(l>>5); acc f32x16[4][2]; epilogue per m74/m101 C/D.

#define H 224
#define W 224
#define NPOS (H*W)          // 50176
#define CI 256
#define CO 256
#define KDIM 2304
#define HP 226              // padded
#define XP_ELEMS (HP*HP*CI) // 13,075,456 shorts
#define AP_ELEMS (CO*KDIM)  // 589,824 shorts

typedef __bf16 bf16x8 __attribute__((ext_vector_type(8)));
typedef float f32x4 __attribute__((ext_vector_type(4)));
typedef float f32x16 __attribute__((ext_vector_type(16)));
typedef unsigned short u16x4 __attribute__((ext_vector_type(4)));
typedef unsigned short u16x8 __attribute__((ext_vector_type(8)));

__device__ __forceinline__ unsigned short f2bf(float f) {
    unsigned int u = __float_as_uint(f);
    u += 0x7fff + ((u >> 16) & 1);   // round-to-nearest-even
    return (unsigned short)(u >> 16);
}

__device__ __forceinline__ void load_lds16(const unsigned short* g, unsigned short* l) {
    __builtin_amdgcn_global_load_lds(
        (const __attribute__((address_space(1))) void*)g,
        (__attribute__((address_space(3))) void*)l,
        16, 0, 0);
}

// ---- fused prep (unchanged from R8): xtrans + weight transform + border zero ----
#define XT_BLOCKS 3136      // 784 * 4
#define WT_BLOCKS 256
#define BORDER_V8 28800     // 230,400 shorts / 8
#define ROW_V8 7232         // 226*256/8
__global__ void prep_kernel(const float* __restrict__ x, const float* __restrict__ w,
                            unsigned short* __restrict__ ap, unsigned short* __restrict__ xp) {
    __shared__ unsigned short smem[64 * 68];
    const int bx = blockIdx.x;
    const int t = threadIdx.x;

    if (bx < XT_BLOCKS) {
        const unsigned int pBase = (unsigned int)(bx % 784) * 64;
        const unsigned int ciBase = (unsigned int)(bx / 784) * 64;
        {
            const int p4 = (t & 15) * 4;
            const int c0 = t >> 4;               // 0..15
#pragma unroll
            for (int i = 0; i < 4; ++i) {
                const int ci_l = c0 + i * 16;
                const f32x4 v = *(const f32x4*)&x[(ciBase + ci_l) * NPOS + pBase + p4];
                u16x4 s;
                s[0] = f2bf(v[0]); s[1] = f2bf(v[1]); s[2] = f2bf(v[2]); s[3] = f2bf(v[3]);
                *(u16x4*)&smem[ci_l * 68 + p4] = s;
            }
        }
        __syncthreads();
        {
            const int ci0 = (t & 7) * 8;
            const int pr = t >> 3;               // 0..31
#pragma unroll
            for (int j = 0; j < 2; ++j) {
                const int p_l = pr + j * 32;
                const unsigned int p = pBase + p_l;
                const unsigned int hi = p / W, wi = p - hi * W;
                u16x8 v;
#pragma unroll
                for (int k = 0; k < 8; ++k) v[k] = smem[(ci0 + k) * 68 + p_l];
                *(u16x8*)&xp[((hi + 1) * HP + (wi + 1)) * CI + ciBase + ci0] = v;
            }
        }
    } else if (bx < XT_BLOCKS + WT_BLOCKS) {
        const int co = bx - XT_BLOCKS;
        const float* wc = w + co * KDIM;
#pragma unroll
        for (int i = 0; i < 9; ++i)
            smem[i * 256 + t] = f2bf(wc[i * 256 + t]);
        __syncthreads();
        unsigned short* apc = ap + co * KDIM;
#pragma unroll
        for (int tap = 0; tap < 9; ++tap)
            apc[tap * 256 + t] = smem[t * 9 + tap];
    } else {
        const int idx = (bx - XT_BLOCKS - WT_BLOCKS) * 256 + t;
        if (idx < BORDER_V8) {
            unsigned short* p;
            if (idx < 2 * ROW_V8) {
                const int r = idx / ROW_V8;
                const int off = idx - r * ROW_V8;
                p = xp + r * (225 * HP * CI) + off * 8;
            } else {
                const int i2 = idx - 2 * ROW_V8;
                const int seg = i2 >> 5;
                const int o = i2 & 31;
                const int hp = 1 + (seg >> 1);
                const int wp = (seg & 1) * 225;
                p = xp + (hp * HP + wp) * CI + o * 8;
            }
            *(u16x8*)p = (u16x8){0, 0, 0, 0, 0, 0, 0, 0};
        }
    }
}

// ---- implicit GEMM, 256x256 tile, BK=64, 8 waves (2Mx4N), wave-tile 128x64 ----
// MFMA 32x32x16_bf16: per wave-tile 4(M) x 2(N) tiles of 32x32, acc f32x16[4][2].
// LDS (shorts): A[pi][kappa] = 4 regions x 8192 at [0,32768); B likewise at +32768.
//   Rows of 32 shorts (4 chunks of 8). Slot s of row r holds global chunk s^((r>>1)&3)
//   (store side unchanged from R12/R13; inverse pre-applied to global source).
// Read (k-step s in {0,1} of a kappa): lane l -> row l&31 (of its 32-tile), chunk
//   c = 2s + (l>>5), slot = c ^ ((r>>1)&3). Bank check: quad8 = 4(r&1) + (c^((r>>1)&3));
//   rows 0..31, both k-halves: every bank-quad exactly 8 lanes. Conflict-free.
// Fragment maps: A row=l&31, k=(l>>5)*8+e (ext of verified 16x16 map); C/D col=l&31,
//   row=(reg&3)+8*(reg>>2)+4*(l>>5)  [m74/m101].
// Sync identical to R13: per kappa-half {12 ds_read ; 2-load stages ; 16 MFMA ;
//   vmcnt(4) ; s_barrier}. vmcnt proof unchanged (4 loads/thread/K-tile in flight
//   semantics identical; tail kt=35 kappa0 uses vmcnt(0)).

#define RD(base, s)                                                             \
    {                                                                           \
        const int cs = ((2 * (s) + hk) ^ sg) * 8;                               \
        _Pragma("unroll")                                                       \
        for (int mi = 0; mi < 4; ++mi)                                          \
            af[mi] = *(const bf16x8*)&lds[(base) + aoff[mi] + cs];              \
        _Pragma("unroll")                                                       \
        for (int ni = 0; ni < 2; ++ni)                                          \
            bf[ni] = *(const bf16x8*)&lds[(base) + boff[ni] + cs];              \
    }

#define MM()                                                                    \
    __builtin_amdgcn_s_setprio(1);                                              \
    _Pragma("unroll")                                                           \
    for (int mi = 0; mi < 4; ++mi)                                              \
        _Pragma("unroll")                                                       \
        for (int ni = 0; ni < 2; ++ni)                                          \
            acc[mi][ni] = __builtin_amdgcn_mfma_f32_32x32x16_bf16(              \
                af[mi], bf[ni], acc[mi][ni], 0, 0, 0);                          \
    __builtin_amdgcn_s_setprio(0);

__global__ __launch_bounds__(512, 1) void gemm_conv_kernel(
    const unsigned short* __restrict__ Ap,   // [256][2304] bf16
    const unsigned short* __restrict__ Xp,   // [226][226][256] bf16
    float* __restrict__ out)                 // [256][50176]
{
    __shared__ unsigned short lds[65536];    // 128 KB

    const int tid = threadIdx.x;
    const int Nb = blockIdx.x;               // 0..195
    const int wave = tid >> 6;               // 0..7
    const int wm = wave >> 2;                // 0..1 (M half: 128 rows)
    const int wn = wave & 3;                 // 0..3 (N quarter: 64 cols)
    const int lane = tid & 63;
    const int ln31 = lane & 31;
    const int hk = lane >> 5;                // k-half selector
    const int sg = (ln31 >> 1) & 3;          // swizzle sigma(row) = row bits 1-2

    int aoff[4], boff[2];
#pragma unroll
    for (int mi = 0; mi < 4; ++mi) aoff[mi] = (wm * 128 + mi * 32 + ln31) * 32;
#pragma unroll
    for (int ni = 0; ni < 2; ++ni) boff[ni] = 32768 + (wn * 64 + ni * 32 + ln31) * 32;

    // ---- staging sources (inverse swizzle pre-applied; unchanged from R12/R13) ----
    const int c4 = (tid & 3) ^ ((tid >> 3) & 3);
    const unsigned short* a_src[2];
    const unsigned short* b_src[2];
#pragma unroll
    for (int j = 0; j < 2; ++j) {
        const int r = j * 128 + (tid >> 2);              // 0..255
        a_src[j] = Ap + r * KDIM + c4 * 8;               // + kt*64 + kappa*32
        unsigned int p = Nb * 256 + r;
        unsigned int hi = p / W, wi = p - hi * W;
        b_src[j] = Xp + (hi * HP + wi) * CI + c4 * 8;    // + tap/ci offset
    }

    f32x16 acc[4][2];
#pragma unroll
    for (int mi = 0; mi < 4; ++mi)
#pragma unroll
        for (int ni = 0; ni < 2; ++ni)
#pragma unroll
            for (int e = 0; e < 16; ++e)
                acc[mi][ni][e] = 0.f;

    auto stageA = [&](int kt, int k) {
        const int dst = ((kt & 1) * 2 + k) * 8192;
        const int off = kt * 64 + k * 32;
#pragma unroll
        for (int j = 0; j < 2; ++j)
            load_lds16(a_src[j] + off, &lds[dst + (j * 8 + wave) * 512]);
    };
    auto stageB = [&](int kt, int k) {
        const int dst = 32768 + ((kt & 1) * 2 + k) * 8192;
        const int tap = kt >> 2;                         // 0..8
        const int dh = (tap * 11) >> 5;                  // tap/3 for tap<=8
        const int dw = tap - dh * 3;
        const int off = (dh * HP + dw) * CI + (kt & 3) * 64 + k * 32;
#pragma unroll
        for (int j = 0; j < 2; ++j)
            load_lds16(b_src[j] + off, &lds[dst + (j * 8 + wave) * 512]);
    };

    bf16x8 af[4], bf[2];

    // ---- prologue: stage K-tile 0 (Ak0,Bk0,Ak1,Bk1 = 8 loads); keep k1 in flight ----
    stageA(0, 0); stageB(0, 0); stageA(0, 1); stageB(0, 1);
    asm volatile("s_waitcnt vmcnt(4)" ::: "memory");     // Ak0,Bk0 landed
    __builtin_amdgcn_s_barrier();

    for (int kt = 0; kt < 36; ++kt) {
        const int b0 = (kt & 1) * 16384;                 // kappa = 0 region
        const int b1 = b0 + 8192;                        // kappa = 1 region
        const bool st = kt < 35;
        // ---- kappa = 0 half: free-run ----
        RD(b0, 0)
        if (st) stageA(kt + 1, 0);
        MM()
        RD(b0, 1)
        if (st) stageB(kt + 1, 0);
        MM()
        if (st) asm volatile("s_waitcnt vmcnt(4)" ::: "memory");
        else    asm volatile("s_waitcnt vmcnt(0)" ::: "memory");
        __builtin_amdgcn_s_barrier();                    // kt's k1 landed, wave-global
        // ---- kappa = 1 half ----
        RD(b1, 0)
        if (st) stageA(kt + 1, 1);
        MM()
        RD(b1, 1)
        if (st) stageB(kt + 1, 1);
        MM()
        if (st) {
            asm volatile("s_waitcnt vmcnt(4)" ::: "memory");
            __builtin_amdgcn_s_barrier();                // kt+1's k0 landed; seals reads
        }
    }

    // ---- epilogue: C/D col = lane&31 (n=p), row = (reg&3) + 8*(reg>>2) + 4*hk ----
    const int colbase = Nb * 256 + wn * 64 + ln31;
    const int rowbase = wm * 128 + 4 * hk;
#pragma unroll
    for (int mi = 0; mi < 4; ++mi)
#pragma unroll
        for (int ni = 0; ni < 2; ++ni)
#pragma unroll
            for (int g = 0; g < 4; ++g)
#pragma unroll
                for (int rr = 0; rr < 4; ++rr)
                    out[(rowbase + mi * 32 + g * 8 + rr) * NPOS + colbase + ni * 32] =
                        acc[mi][ni][g * 4 + rr];
}

extern "C" void kernel_launch(void* const* d_in, const int* in_sizes, int n_in,
                              void* d_out, int out_size, void* d_ws, size_t ws_size,
                              hipStream_t stream) {
    const float* x = (const float*)d_in[0];       // [1,256,224,224]
    const float* w = (const float*)d_in[1];       // [256,256,3,3]
    float* out = (float*)d_out;                   // [256,224,224]

    unsigned short* xp = (unsigned short*)d_ws;        // 13,075,456 shorts
    unsigned short* ap = xp + XP_ELEMS;                // 589,824 shorts

    prep_kernel<<<XT_BLOCKS + WT_BLOCKS + 113, 256, 0, stream>>>(x, w, ap, xp);
    gemm_conv_kernel<<<dim3(NPOS / 256), 512, 0, stream>>>(ap, xp, out);
}